// Round 1
// baseline (488.406 us; speedup 1.0000x reference)
//
#include <hip/hip_runtime.h>
#include <cstdint>
#include <cstddef>

typedef unsigned short u16;
typedef __attribute__((ext_vector_type(8))) __bf16 bf16x8;
typedef __attribute__((ext_vector_type(4))) float f32x4;

// ---------------- helpers ----------------

__device__ __forceinline__ u16 f2bf(float f) {
    union { float f; unsigned u; } v; v.f = f;
    unsigned r = v.u + 0x7fffu + ((v.u >> 16) & 1u);   // round-to-nearest-even
    return (u16)(r >> 16);
}

// J1 Bessel, Numerical Recipes single-precision rational/asymptotic approx,
// matching the reference formula. The |x|>=8 branch is wave-guarded: for
// t@W1+b1 ~ N(0,1) it is essentially never taken.
__device__ __forceinline__ float j1f_approx(float x) {
    float ax = fabsf(x);
    float y = x * x;
    float num = x * (7.2362614232e10f + y * (-7.895059235e9f + y * (2.423968531e8f
              + y * (-2.972611439e6f + y * (1.570448260e4f + y * (-3.016036606e1f))))));
    float den = 1.44725228442e11f + y * (2.300535178e9f + y * (1.858330474e7f
              + y * (9.944743394e4f + y * (3.769991397e2f + y))));
    float r = num / den;
    if (__any(ax >= 8.0f)) {
        float z  = 8.0f / ax;
        float yy = z * z;
        float xx = ax - 2.356194491f;
        float p1 = 1.0f + yy * (0.183105e-2f + yy * (-0.3516396496e-4f
                 + yy * (0.2457520174e-5f + yy * (-0.240337019e-6f))));
        float p2 = 0.04687499995f + yy * (-0.2002690873e-3f + yy * (0.8449199096e-5f
                 + yy * (-0.88228987e-6f + yy * 0.105787412e-6f)));
        float big = sqrtf(0.636619772f / ax) * (__cosf(xx) * p1 - z * __sinf(xx) * p2);
        big = copysignf(big, x);
        if (ax >= 8.0f) r = big;
    }
    return r;
}

// ---------------- prep kernels ----------------

__global__ void k_f32_to_bf16(const float* __restrict__ in, u16* __restrict__ out, int n) {
    int i = blockIdx.x * 256 + threadIdx.x;
    if (i < n) out[i] = f2bf(in[i]);
}

// out[n][k] = bf16(in[k][n]); K,N multiples of 32
__global__ void k_transpose_bf16(const float* __restrict__ in, u16* __restrict__ out,
                                 int K, int N) {
    __shared__ float tile[32][33];
    int n0 = blockIdx.x * 32, k0 = blockIdx.y * 32;
    int tx = threadIdx.x, ty = threadIdx.y;   // 32 x 8
    #pragma unroll
    for (int i = ty; i < 32; i += 8)
        tile[i][tx] = in[(size_t)(k0 + i) * N + n0 + tx];
    __syncthreads();
    #pragma unroll
    for (int i = ty; i < 32; i += 8)
        out[(size_t)(n0 + i) * K + k0 + tx] = f2bf(tile[tx][i]);
}

__global__ void k_init_out(const float* __restrict__ b3, float* __restrict__ out, int n) {
    int i = blockIdx.x * 256 + threadIdx.x;
    if (i < n) out[i] = b3[i & 63];
}

// ---------------- GEMM (m97 128^2 structure, B^T input) ----------------
// C[M,N] = A[M,K] * Bt[N,K]^T.  256 threads = 4 waves in 2x2 arrangement.
// EPI: 0 = J1(v+bias)->bf16, 1 = sin(v+bias)->bf16, 2 = atomicAdd f32.

#define BK 32

template<int BM, int BN, int WTM, int WTN, int EPI>
__global__ __launch_bounds__(256)
void k_gemm_bt(const u16* __restrict__ A, int lda,
               const u16* __restrict__ Bt, int ldb,
               const float* __restrict__ bias,
               void* __restrict__ Cout, int ldc,
               int kstart, int klen)
{
    __shared__ __align__(16) u16 Alds[BM * BK];
    __shared__ __align__(16) u16 Blds[BN * BK];

    const int tid  = threadIdx.x;
    const int lane = tid & 63;
    const int wid  = tid >> 6;
    const int wrow = (wid >> 1) * (WTM * 16);
    const int wcol = (wid & 1) * (WTN * 16);
    const int lr   = lane & 15;
    const int lkb  = (lane >> 4) * 8;       // k element offset within fragment

    const int brow = blockIdx.y * BM;
    const int bcol = blockIdx.x * BN;
    const int k0 = kstart + blockIdx.z * klen;
    const int k1 = k0 + klen;

    f32x4 acc[WTM][WTN] = {};

    for (int kk = k0; kk < k1; kk += BK) {
        // stage A tile (BM x 32 bf16) via direct global->LDS, 16B per lane
        #pragma unroll
        for (int c = tid; c < BM * 4; c += 256) {
            const u16* g = A + (size_t)(brow + (c >> 2)) * lda + kk + (c & 3) * 8;
            __builtin_amdgcn_global_load_lds(
                (const __attribute__((address_space(1))) void*)g,
                (__attribute__((address_space(3))) void*)(&Alds[c * 8]), 16, 0, 0);
        }
        // stage B tile (BN x 32 bf16)
        #pragma unroll
        for (int c = tid; c < BN * 4; c += 256) {
            const u16* g = Bt + (size_t)(bcol + (c >> 2)) * ldb + kk + (c & 3) * 8;
            __builtin_amdgcn_global_load_lds(
                (const __attribute__((address_space(1))) void*)g,
                (__attribute__((address_space(3))) void*)(&Blds[c * 8]), 16, 0, 0);
        }
        __syncthreads();

        bf16x8 af[WTM], bfr[WTN];
        #pragma unroll
        for (int m = 0; m < WTM; ++m)
            af[m] = *(const bf16x8*)&Alds[(wrow + m * 16 + lr) * BK + lkb];
        #pragma unroll
        for (int n = 0; n < WTN; ++n)
            bfr[n] = *(const bf16x8*)&Blds[(wcol + n * 16 + lr) * BK + lkb];
        #pragma unroll
        for (int m = 0; m < WTM; ++m)
            #pragma unroll
            for (int n = 0; n < WTN; ++n)
                acc[m][n] = __builtin_amdgcn_mfma_f32_16x16x32_bf16(
                                af[m], bfr[n], acc[m][n], 0, 0, 0);
        __syncthreads();
    }

    // epilogue; C/D frag mapping: col = lane&15, row = (lane>>4)*4 + r
    const int rbase = brow + wrow + (lane >> 4) * 4;
    const int cbase = bcol + wcol + lr;
    #pragma unroll
    for (int n = 0; n < WTN; ++n) {
        const int col = cbase + n * 16;
        float bv = 0.0f;
        if constexpr (EPI != 2) bv = bias[col];
        #pragma unroll
        for (int m = 0; m < WTM; ++m) {
            #pragma unroll
            for (int r = 0; r < 4; ++r) {
                const int row = rbase + m * 16 + r;
                float v = acc[m][n][r];
                if constexpr (EPI == 0) {
                    ((u16*)Cout)[(size_t)row * ldc + col] = f2bf(j1f_approx(v + bv));
                } else if constexpr (EPI == 1) {
                    ((u16*)Cout)[(size_t)row * ldc + col] = f2bf(__sinf(v + bv));
                } else {
                    atomicAdd(&((float*)Cout)[(size_t)row * ldc + col], v);
                }
            }
        }
    }
}

// ---------------- launch ----------------

extern "C" void kernel_launch(void* const* d_in, const int* in_sizes, int n_in,
                              void* d_out, int out_size, void* d_ws, size_t ws_size,
                              hipStream_t stream) {
    const float* t  = (const float*)d_in[0];
    const float* W1 = (const float*)d_in[1];
    const float* b1 = (const float*)d_in[2];
    const float* W2 = (const float*)d_in[3];
    const float* b2 = (const float*)d_in[4];
    const float* W3 = (const float*)d_in[5];
    const float* b3 = (const float*)d_in[6];
    float* out = (float*)d_out;

    constexpr int B = 32768, Din = 64, H = 2048, Dout = 64;

    char* p = (char*)d_ws;
    u16* t_bf = (u16*)p; p += (size_t)B * Din * 2;
    u16* w1t  = (u16*)p; p += (size_t)H * Din * 2;
    u16* w2t  = (u16*)p; p += (size_t)H * H * 2;
    u16* w3t  = (u16*)p; p += (size_t)Dout * H * 2;
    size_t fixed = (size_t)(p - (char*)d_ws);

    // pick largest row-chunk R whose h1+h2 fit the workspace
    int R = B;
    while (R > 512 && fixed + (size_t)2 * R * H * 2 > ws_size) R >>= 1;
    u16* h1 = (u16*)p;
    u16* h2 = (u16*)(p + (size_t)R * H * 2);

    // prep: convert t, transpose+convert weights, init out with b3
    k_f32_to_bf16<<<(B * Din + 255) / 256, 256, 0, stream>>>(t, t_bf, B * Din);
    k_transpose_bf16<<<dim3(H / 32, Din / 32), dim3(32, 8), 0, stream>>>(W1, w1t, Din, H);
    k_transpose_bf16<<<dim3(H / 32, H / 32), dim3(32, 8), 0, stream>>>(W2, w2t, H, H);
    k_transpose_bf16<<<dim3(Dout / 32, H / 32), dim3(32, 8), 0, stream>>>(W3, w3t, H, Dout);
    k_init_out<<<(out_size + 255) / 256, 256, 0, stream>>>(b3, out, out_size);

    const int SPLITS = 4;
    for (int c0 = 0; c0 < B; c0 += R) {
        const u16* tA = t_bf + (size_t)c0 * Din;
        // GEMM1: h1 = J1(t@W1 + b1)   [R x H], K=64
        k_gemm_bt<128, 128, 4, 4, 0><<<dim3(H / 128, R / 128), 256, 0, stream>>>(
            tA, Din, w1t, Din, b1, h1, H, 0, Din);
        // GEMM2: h2 = sin(h1@W2 + b2) [R x H], K=2048
        k_gemm_bt<128, 128, 4, 4, 1><<<dim3(H / 128, R / 128), 256, 0, stream>>>(
            h1, H, w2t, H, b2, h2, H, 0, H);
        // GEMM3: out += h2@W3 (b3 pre-initialized), split-K=4, atomic f32
        k_gemm_bt<128, 64, 4, 2, 2><<<dim3(1, R / 128, SPLITS), 256, 0, stream>>>(
            h2, H, w3t, H, nullptr, out + (size_t)c0 * Dout, Dout, 0, H / SPLITS);
    }
}

// Round 3
// 410.409 us; speedup vs baseline: 1.1900x; 1.1900x over previous
//
#include <hip/hip_runtime.h>
#include <cstdint>
#include <cstddef>

typedef unsigned short u16;
typedef __attribute__((ext_vector_type(8))) __bf16 bf16x8;
typedef __attribute__((ext_vector_type(4))) float f32x4;

// ---------------- helpers ----------------

__device__ __forceinline__ u16 f2bf(float f) {
    union { float f; unsigned u; } v; v.f = f;
    unsigned r = v.u + 0x7fffu + ((v.u >> 16) & 1u);   // round-to-nearest-even
    return (u16)(r >> 16);
}

__device__ __forceinline__ float j1f_approx(float x) {
    float ax = fabsf(x);
    float y = x * x;
    float num = x * (7.2362614232e10f + y * (-7.895059235e9f + y * (2.423968531e8f
              + y * (-2.972611439e6f + y * (1.570448260e4f + y * (-3.016036606e1f))))));
    float den = 1.44725228442e11f + y * (2.300535178e9f + y * (1.858330474e7f
              + y * (9.944743394e4f + y * (3.769991397e2f + y))));
    float r = num / den;
    if (__any(ax >= 8.0f)) {
        float z  = 8.0f / ax;
        float yy = z * z;
        float xx = ax - 2.356194491f;
        float p1 = 1.0f + yy * (0.183105e-2f + yy * (-0.3516396496e-4f
                 + yy * (0.2457520174e-5f + yy * (-0.240337019e-6f))));
        float p2 = 0.04687499995f + yy * (-0.2002690873e-3f + yy * (0.8449199096e-5f
                 + yy * (-0.88228987e-6f + yy * 0.105787412e-6f)));
        float big = sqrtf(0.636619772f / ax) * (__cosf(xx) * p1 - z * __sinf(xx) * p2);
        big = copysignf(big, x);
        if (ax >= 8.0f) r = big;
    }
    return r;
}

// ---------------- prep kernels ----------------

__global__ void k_f32_to_bf16(const float* __restrict__ in, u16* __restrict__ out, int n) {
    int i = blockIdx.x * 256 + threadIdx.x;
    if (i < n) out[i] = f2bf(in[i]);
}

__global__ void k_transpose_bf16(const float* __restrict__ in, u16* __restrict__ out,
                                 int K, int N) {
    __shared__ float tile[32][33];
    int n0 = blockIdx.x * 32, k0 = blockIdx.y * 32;
    int tx = threadIdx.x, ty = threadIdx.y;   // 32 x 8
    #pragma unroll
    for (int i = ty; i < 32; i += 8)
        tile[i][tx] = in[(size_t)(k0 + i) * N + n0 + tx];
    __syncthreads();
    #pragma unroll
    for (int i = ty; i < 32; i += 8)
        out[(size_t)(n0 + i) * K + k0 + tx] = f2bf(tile[tx][i]);
}

__global__ void k_init_out(const float* __restrict__ b3, float* __restrict__ out, int n) {
    int i = blockIdx.x * 256 + threadIdx.x;
    if (i < n) out[i] = b3[i & 63];
}

// ---------------- small GEMM (m97 128^2 structure) for GEMM1 / GEMM3 ----------------
// C[M,N] = A[M,K] * Bt[N,K]^T.  EPI: 0 = J1(v+bias)->bf16, 2 = atomicAdd f32.

#define BK 32

template<int BM, int BN, int WTM, int WTN, int EPI>
__global__ __launch_bounds__(256)
void k_gemm_bt(const u16* __restrict__ A, int lda,
               const u16* __restrict__ Bt, int ldb,
               const float* __restrict__ bias,
               void* __restrict__ Cout, int ldc,
               int kstart, int klen)
{
    __shared__ __align__(16) u16 Alds[BM * BK];
    __shared__ __align__(16) u16 Blds[BN * BK];

    const int tid  = threadIdx.x;
    const int lane = tid & 63;
    const int wid  = tid >> 6;
    const int wrow = (wid >> 1) * (WTM * 16);
    const int wcol = (wid & 1) * (WTN * 16);
    const int lr   = lane & 15;
    const int lkb  = (lane >> 4) * 8;

    const int brow = blockIdx.y * BM;
    const int bcol = blockIdx.x * BN;
    const int k0 = kstart + blockIdx.z * klen;
    const int k1 = k0 + klen;

    f32x4 acc[WTM][WTN] = {};

    for (int kk = k0; kk < k1; kk += BK) {
        #pragma unroll
        for (int c = tid; c < BM * 4; c += 256) {
            const u16* g = A + (size_t)(brow + (c >> 2)) * lda + kk + (c & 3) * 8;
            __builtin_amdgcn_global_load_lds(
                (const __attribute__((address_space(1))) void*)g,
                (__attribute__((address_space(3))) void*)(&Alds[c * 8]), 16, 0, 0);
        }
        #pragma unroll
        for (int c = tid; c < BN * 4; c += 256) {
            const u16* g = Bt + (size_t)(bcol + (c >> 2)) * ldb + kk + (c & 3) * 8;
            __builtin_amdgcn_global_load_lds(
                (const __attribute__((address_space(1))) void*)g,
                (__attribute__((address_space(3))) void*)(&Blds[c * 8]), 16, 0, 0);
        }
        __syncthreads();

        bf16x8 af[WTM], bfr[WTN];
        #pragma unroll
        for (int m = 0; m < WTM; ++m)
            af[m] = *(const bf16x8*)&Alds[(wrow + m * 16 + lr) * BK + lkb];
        #pragma unroll
        for (int n = 0; n < WTN; ++n)
            bfr[n] = *(const bf16x8*)&Blds[(wcol + n * 16 + lr) * BK + lkb];
        #pragma unroll
        for (int m = 0; m < WTM; ++m)
            #pragma unroll
            for (int n = 0; n < WTN; ++n)
                acc[m][n] = __builtin_amdgcn_mfma_f32_16x16x32_bf16(
                                af[m], bfr[n], acc[m][n], 0, 0, 0);
        __syncthreads();
    }

    const int rbase = brow + wrow + (lane >> 4) * 4;
    const int cbase = bcol + wcol + lr;
    #pragma unroll
    for (int n = 0; n < WTN; ++n) {
        const int col = cbase + n * 16;
        float bv = 0.0f;
        if constexpr (EPI != 2) bv = bias[col];
        #pragma unroll
        for (int m = 0; m < WTM; ++m) {
            #pragma unroll
            for (int r = 0; r < 4; ++r) {
                const int row = rbase + m * 16 + r;
                float v = acc[m][n][r];
                if constexpr (EPI == 0) {
                    ((u16*)Cout)[(size_t)row * ldc + col] = f2bf(j1f_approx(v + bv));
                } else {
                    atomicAdd(&((float*)Cout)[(size_t)row * ldc + col], v);
                }
            }
        }
    }
}

// ---------------- 256^2 8-phase GEMM for GEMM2 (race-free staging schedule) ----
// C[M,N] = A[M,K]*Bt[N,K]^T, epilogue sin(v+bias)->bf16.
// 512 threads = 8 waves (2 M-halves x 4 N-quarters). BK=64, dbuf LDS 128 KiB.
// Staging plan (iteration t reads tile t from buffer b=t&1):
//   ph0: stage B-half0(t+1) -> buf b^1 (old contents consumed last iter)
//   ph1: stage B-half1(t+1) -> buf b^1
//   ph3: stage A-half0/1(t+2) -> buf b A-regions (last read ph2, barrier between)
// End of iter: vmcnt(4) + barrier  (all waves wait -> everything except the 4
// in-flight A(t+2) loads has landed; those are read 2 tiles later).

__global__ __launch_bounds__(512, 2)
void k_gemm256(const u16* __restrict__ A, int lda,
               const u16* __restrict__ Bt, int ldb,
               const float* __restrict__ bias,
               u16* __restrict__ C, int ldc, int K)
{
    __shared__ __align__(16) u16 lds[65536];   // 128 KiB

    const int tid  = threadIdx.x;
    const int lane = tid & 63;
    const int wid  = tid >> 6;
    const int wr   = wid >> 2;        // 0..1  (M half, 128 rows)
    const int wc   = wid & 3;         // 0..3  (N quarter, 64 cols)
    const int lr   = lane & 15;
    const int kq   = lane >> 4;       // 0..3

    // XCD-bijective block swizzle (gridDim.x == 8 here, so nwg % 8 == 0)
    const int nwg  = gridDim.x * gridDim.y;
    const int bid0 = blockIdx.y * gridDim.x + blockIdx.x;
    const int wg   = (bid0 & 7) * (nwg >> 3) + (bid0 >> 3);
    const int bx   = wg % gridDim.x;
    const int by   = wg / gridDim.x;
    const int brow = by * 256;
    const int bcol = bx * 256;

    const int nT = K >> 6;            // K-tiles of 64

    // stage(tile, q): q=0/1 -> A half0/1, q=2/3 -> B half0/1.  Linear LDS dest
    // (global_load_lds), inverse-swizzled global source; reads apply same XOR.
    auto stage = [&](int tile, int q) {
        const int b = tile & 1, h = q & 1;
        const u16* gb; int ldg; u16* lb;
        if (q < 2) { gb = A  + (size_t)(brow + h * 128) * lda; ldg = lda;
                     lb = &lds[b * 16384 + h * 8192]; }
        else       { gb = Bt + (size_t)(bcol + h * 128) * ldb; ldg = ldb;
                     lb = &lds[32768 + b * 16384 + h * 8192]; }
        #pragma unroll
        for (int r = 0; r < 2; ++r) {
            const int c = r * 512 + tid;
            const int row = c >> 3, slot = c & 7;
            const u16* g = gb + (size_t)row * ldg + tile * 64 + ((slot ^ (row & 7)) << 3);
            __builtin_amdgcn_global_load_lds(
                (const __attribute__((address_space(1))) void*)g,
                (__attribute__((address_space(3))) void*)(lb + c * 8), 16, 0, 0);
        }
    };

    // swizzled ds_read offsets (u16 units), all compile-time-indexed
    int a_off[8][2], b_off[4][2];
    #pragma unroll
    for (int m = 0; m < 8; ++m) {
        const int row = m * 16 + lr;
        #pragma unroll
        for (int ks = 0; ks < 2; ++ks)
            a_off[m][ks] = row * 64 + ((ks * 32 + kq * 8) ^ ((row & 7) << 3));
    }
    #pragma unroll
    for (int n = 0; n < 4; ++n) {
        const int row = (wc & 1) * 64 + n * 16 + lr;
        #pragma unroll
        for (int ks = 0; ks < 2; ++ks)
            b_off[n][ks] = row * 64 + ((ks * 32 + kq * 8) ^ ((row & 7) << 3));
    }

    f32x4 acc[8][4] = {};
    bf16x8 af[4][2], bf[2][2];

#define RD_A(mh) { _Pragma("unroll") for (int m = 0; m < 4; ++m) \
                   _Pragma("unroll") for (int ks = 0; ks < 2; ++ks) \
                       af[m][ks] = *(const bf16x8*)&la[a_off[(mh)*4 + m][ks]]; }
#define RD_B(nh) { _Pragma("unroll") for (int j = 0; j < 2; ++j) \
                   _Pragma("unroll") for (int ks = 0; ks < 2; ++ks) \
                       bf[j][ks] = *(const bf16x8*)&lb_[b_off[(nh)*2 + j][ks]]; }
#define MMA(mh, nh) { __builtin_amdgcn_s_setprio(1); \
                      _Pragma("unroll") for (int m = 0; m < 4; ++m) \
                      _Pragma("unroll") for (int j = 0; j < 2; ++j) \
                      _Pragma("unroll") for (int ks = 0; ks < 2; ++ks) \
                          acc[(mh)*4 + m][(nh)*2 + j] = \
                              __builtin_amdgcn_mfma_f32_16x16x32_bf16( \
                                  af[m][ks], bf[j][ks], acc[(mh)*4 + m][(nh)*2 + j], 0, 0, 0); \
                      __builtin_amdgcn_s_setprio(0); }
#define BARRIER()  asm volatile("s_barrier" ::: "memory")
#define LGKM0()    asm volatile("s_waitcnt lgkmcnt(0)" ::: "memory")

    // prologue: tile0 fully + tile1's A (steady state stages A one iter early)
    stage(0, 0); stage(0, 1); stage(0, 2); stage(0, 3);
    if (nT > 1) {
        stage(1, 0); stage(1, 1);
        asm volatile("s_waitcnt vmcnt(4)" ::: "memory");
    } else {
        asm volatile("s_waitcnt vmcnt(0)" ::: "memory");
    }
    BARRIER();

    for (int t = 0; t < nT; ++t) {
        const int b = t & 1;
        const u16* la  = &lds[b * 16384 + wr * 8192];
        const u16* lb_ = &lds[32768 + b * 16384 + (wc >> 1) * 8192];

        // phase 0: quadrant (0,0)
        RD_A(0); RD_B(0);
        if (t + 1 < nT) stage(t + 1, 2);
        BARRIER(); LGKM0();
        MMA(0, 0);
        BARRIER();

        // phase 1: quadrant (0,1) — A regs reused
        RD_B(1);
        if (t + 1 < nT) stage(t + 1, 3);
        BARRIER(); LGKM0();
        MMA(0, 1);
        BARRIER();

        // phase 2: quadrant (1,1) — B regs reused
        RD_A(1);
        BARRIER(); LGKM0();
        MMA(1, 1);
        BARRIER();

        // phase 3: quadrant (1,0) — A regs reused
        RD_B(0);
        if (t + 2 < nT) { stage(t + 2, 0); stage(t + 2, 1); }
        BARRIER(); LGKM0();
        MMA(1, 0);
        if (t < nT - 2)       { asm volatile("s_waitcnt vmcnt(4)" ::: "memory"); }
        else if (t == nT - 2) { asm volatile("s_waitcnt vmcnt(0)" ::: "memory"); }
        BARRIER();
    }

#undef RD_A
#undef RD_B
#undef MMA
#undef BARRIER
#undef LGKM0

    // epilogue: sin(v + bias) -> bf16.  C/D map: col = lane&15, row = kq*4 + r
    #pragma unroll
    for (int n = 0; n < 4; ++n) {
        const int col = bcol + wc * 64 + n * 16 + lr;
        const float bv = bias[col];
        #pragma unroll
        for (int m = 0; m < 8; ++m) {
            const int row = brow + wr * 128 + m * 16 + kq * 4;
            #pragma unroll
            for (int r = 0; r < 4; ++r)
                C[(size_t)(row + r) * ldc + col] = f2bf(__sinf(acc[m][n][r] + bv));
        }
    }
}

// ---------------- launch ----------------

extern "C" void kernel_launch(void* const* d_in, const int* in_sizes, int n_in,
                              void* d_out, int out_size, void* d_ws, size_t ws_size,
                              hipStream_t stream) {
    const float* t  = (const float*)d_in[0];
    const float* W1 = (const float*)d_in[1];
    const float* b1 = (const float*)d_in[2];
    const float* W2 = (const float*)d_in[3];
    const float* b2 = (const float*)d_in[4];
    const float* W3 = (const float*)d_in[5];
    const float* b3 = (const float*)d_in[6];
    float* out = (float*)d_out;

    constexpr int B = 32768, Din = 64, H = 2048, Dout = 64;

    char* p = (char*)d_ws;
    u16* t_bf = (u16*)p; p += (size_t)B * Din * 2;
    u16* w1t  = (u16*)p; p += (size_t)H * Din * 2;
    u16* w2t  = (u16*)p; p += (size_t)H * H * 2;
    u16* w3t  = (u16*)p; p += (size_t)Dout * H * 2;
    size_t fixed = (size_t)(p - (char*)d_ws);

    int R = B;
    while (R > 512 && fixed + (size_t)2 * R * H * 2 > ws_size) R >>= 1;
    u16* h1 = (u16*)p;
    u16* h2 = (u16*)(p + (size_t)R * H * 2);

    k_f32_to_bf16<<<(B * Din + 255) / 256, 256, 0, stream>>>(t, t_bf, B * Din);
    k_transpose_bf16<<<dim3(H / 32, Din / 32), dim3(32, 8), 0, stream>>>(W1, w1t, Din, H);
    k_transpose_bf16<<<dim3(H / 32, H / 32), dim3(32, 8), 0, stream>>>(W2, w2t, H, H);
    k_transpose_bf16<<<dim3(Dout / 32, H / 32), dim3(32, 8), 0, stream>>>(W3, w3t, H, Dout);
    k_init_out<<<(out_size + 255) / 256, 256, 0, stream>>>(b3, out, out_size);

    const int SPLITS = 4;
    for (int c0 = 0; c0 < B; c0 += R) {
        const u16* tA = t_bf + (size_t)c0 * Din;
        // GEMM1: h1 = J1(t@W1 + b1)   [R x H], K=64
        k_gemm_bt<128, 128, 4, 4, 0><<<dim3(H / 128, R / 128), 256, 0, stream>>>(
            tA, Din, w1t, Din, b1, h1, H, 0, Din);
        // GEMM2: h2 = sin(h1@W2 + b2) [R x H], K=2048 — 256^2 8-phase kernel
        k_gemm256<<<dim3(H / 256, R / 256), 512, 0, stream>>>(
            h1, H, w2t, H, b2, h2, H, H);
        // GEMM3: out += h2@W3 (b3 pre-initialized), split-K=4, atomic f32
        k_gemm_bt<128, 64, 4, 2, 2><<<dim3(1, R / 128, SPLITS), 256, 0, stream>>>(
            h2, H, w3t, H, nullptr, out + (size_t)c0 * Dout, Dout, 0, H / SPLITS);
    }
}

// Round 4
// 388.161 us; speedup vs baseline: 1.2583x; 1.0573x over previous
//
#include <hip/hip_runtime.h>
#include <cstdint>
#include <cstddef>

typedef unsigned short u16;
typedef __attribute__((ext_vector_type(8))) __bf16 bf16x8;
typedef __attribute__((ext_vector_type(4))) float f32x4;

#define AS1(p) ((const __attribute__((address_space(1))) void*)(p))
#define AS3(p) ((__attribute__((address_space(3))) void*)(p))

// ---------------- helpers ----------------

__device__ __forceinline__ u16 f2bf(float f) {
    union { float f; unsigned u; } v; v.f = f;
    unsigned r = v.u + 0x7fffu + ((v.u >> 16) & 1u);   // round-to-nearest-even
    return (u16)(r >> 16);
}

__device__ __forceinline__ float j1f_approx(float x) {
    float ax = fabsf(x);
    float y = x * x;
    float num = x * (7.2362614232e10f + y * (-7.895059235e9f + y * (2.423968531e8f
              + y * (-2.972611439e6f + y * (1.570448260e4f + y * (-3.016036606e1f))))));
    float den = 1.44725228442e11f + y * (2.300535178e9f + y * (1.858330474e7f
              + y * (9.944743394e4f + y * (3.769991397e2f + y))));
    float r = num / den;
    if (__any(ax >= 8.0f)) {
        float z  = 8.0f / ax;
        float yy = z * z;
        float xx = ax - 2.356194491f;
        float p1 = 1.0f + yy * (0.183105e-2f + yy * (-0.3516396496e-4f
                 + yy * (0.2457520174e-5f + yy * (-0.240337019e-6f))));
        float p2 = 0.04687499995f + yy * (-0.2002690873e-3f + yy * (0.8449199096e-5f
                 + yy * (-0.88228987e-6f + yy * 0.105787412e-6f)));
        float big = sqrtf(0.636619772f / ax) * (__cosf(xx) * p1 - z * __sinf(xx) * p2);
        big = copysignf(big, x);
        if (ax >= 8.0f) r = big;
    }
    return r;
}

// ---------------- prep kernels ----------------

__global__ void k_f32_to_bf16(const float* __restrict__ in, u16* __restrict__ out, int n) {
    int i = blockIdx.x * 256 + threadIdx.x;
    if (i < n) out[i] = f2bf(in[i]);
}

__global__ void k_transpose_bf16(const float* __restrict__ in, u16* __restrict__ out,
                                 int K, int N) {
    __shared__ float tile[32][33];
    int n0 = blockIdx.x * 32, k0 = blockIdx.y * 32;
    int tx = threadIdx.x, ty = threadIdx.y;   // 32 x 8
    #pragma unroll
    for (int i = ty; i < 32; i += 8)
        tile[i][tx] = in[(size_t)(k0 + i) * N + n0 + tx];
    __syncthreads();
    #pragma unroll
    for (int i = ty; i < 32; i += 8)
        out[(size_t)(n0 + i) * K + k0 + tx] = f2bf(tile[tx][i]);
}

__global__ void k_init_out(const float* __restrict__ b3, float* __restrict__ out, int n) {
    int i = blockIdx.x * 256 + threadIdx.x;
    if (i < n) out[i] = b3[i & 63];
}

// ---------------- small GEMM (m97 128^2 structure) for GEMM1 / GEMM3 ----------------
// C[M,N] = A[M,K] * Bt[N,K]^T.  EPI: 0 = J1(v+bias)->bf16, 2 = atomicAdd f32.

#define BK 32

template<int BM, int BN, int WTM, int WTN, int EPI>
__global__ __launch_bounds__(256)
void k_gemm_bt(const u16* __restrict__ A, int lda,
               const u16* __restrict__ Bt, int ldb,
               const float* __restrict__ bias,
               void* __restrict__ Cout, int ldc,
               int kstart, int klen)
{
    __shared__ __align__(16) u16 Alds[BM * BK];
    __shared__ __align__(16) u16 Blds[BN * BK];

    const int tid  = threadIdx.x;
    const int lane = tid & 63;
    const int wid  = tid >> 6;
    const int wrow = (wid >> 1) * (WTM * 16);
    const int wcol = (wid & 1) * (WTN * 16);
    const int lr   = lane & 15;
    const int lkb  = (lane >> 4) * 8;

    const int brow = blockIdx.y * BM;
    const int bcol = blockIdx.x * BN;
    const int k0 = kstart + blockIdx.z * klen;
    const int k1 = k0 + klen;

    f32x4 acc[WTM][WTN] = {};

    for (int kk = k0; kk < k1; kk += BK) {
        #pragma unroll
        for (int c = tid; c < BM * 4; c += 256) {
            const u16* g = A + (size_t)(brow + (c >> 2)) * lda + kk + (c & 3) * 8;
            __builtin_amdgcn_global_load_lds(AS1(g), AS3(&Alds[c * 8]), 16, 0, 0);
        }
        #pragma unroll
        for (int c = tid; c < BN * 4; c += 256) {
            const u16* g = Bt + (size_t)(bcol + (c >> 2)) * ldb + kk + (c & 3) * 8;
            __builtin_amdgcn_global_load_lds(AS1(g), AS3(&Blds[c * 8]), 16, 0, 0);
        }
        __syncthreads();

        bf16x8 af[WTM], bfr[WTN];
        #pragma unroll
        for (int m = 0; m < WTM; ++m)
            af[m] = *(const bf16x8*)&Alds[(wrow + m * 16 + lr) * BK + lkb];
        #pragma unroll
        for (int n = 0; n < WTN; ++n)
            bfr[n] = *(const bf16x8*)&Blds[(wcol + n * 16 + lr) * BK + lkb];
        #pragma unroll
        for (int m = 0; m < WTM; ++m)
            #pragma unroll
            for (int n = 0; n < WTN; ++n)
                acc[m][n] = __builtin_amdgcn_mfma_f32_16x16x32_bf16(
                                af[m], bfr[n], acc[m][n], 0, 0, 0);
        __syncthreads();
    }

    const int rbase = brow + wrow + (lane >> 4) * 4;
    const int cbase = bcol + wcol + lr;
    #pragma unroll
    for (int n = 0; n < WTN; ++n) {
        const int col = cbase + n * 16;
        float bv = 0.0f;
        if constexpr (EPI != 2) bv = bias[col];
        #pragma unroll
        for (int m = 0; m < WTM; ++m) {
            #pragma unroll
            for (int r = 0; r < 4; ++r) {
                const int row = rbase + m * 16 + r;
                float v = acc[m][n][r];
                if constexpr (EPI == 0) {
                    ((u16*)Cout)[(size_t)row * ldc + col] = f2bf(j1f_approx(v + bv));
                } else {
                    atomicAdd(&((float*)Cout)[(size_t)row * ldc + col], v);
                }
            }
        }
    }
}

// ---------------- 256^2 8-phase GEMM for GEMM2 (pipelined ds_reads) ----------
// C[M,N] = A[M,K]*Bt[N,K]^T, epilogue sin(v+bias)->bf16.
// 512 threads = 8 waves (2 M-halves x 4 N-quarters). BK=64, dbuf LDS 128 KiB.
// v2: ds_reads for phase p+1 issue right after phase p's MFMA cluster (overlap
// matrix pipe); compiler emits counted lgkmcnt before the consuming MFMA.
// B0 fragments kept in regs across the K-tile (no re-read at phase 3).
// Staging (iter t reads tile t from buf b=t&1):
//   ph0: B-h0(t+1)->buf b^1 ; ph1: B-h1(t+1)->buf b^1 ; ph3: A-h0/h1(t+2)->buf b
// End of iter: vmcnt(4) + barrier (leaves only A(t+2)'s 4 loads in flight).

__global__ __launch_bounds__(512, 2)
void k_gemm256(const u16* __restrict__ A, int lda,
               const u16* __restrict__ Bt, int ldb,
               const float* __restrict__ bias,
               u16* __restrict__ C, int ldc, int K)
{
    __shared__ __align__(16) u16 lds[65536];   // 128 KiB

    const int tid  = threadIdx.x;
    const int lane = tid & 63;
    const int wid  = tid >> 6;
    const int wr   = wid >> 2;        // 0..1  (M half, 128 rows)
    const int wc   = wid & 3;         // 0..3  (N quarter, 64 cols)
    const int lr   = lane & 15;
    const int kq   = lane >> 4;       // 0..3

    // XCD-bijective block swizzle (gridDim.x == 8 -> nwg % 8 == 0)
    const int nwg  = gridDim.x * gridDim.y;
    const int bid0 = blockIdx.y * gridDim.x + blockIdx.x;
    const int wg   = (bid0 & 7) * (nwg >> 3) + (bid0 >> 3);
    const int bx   = wg % gridDim.x;
    const int by   = wg / gridDim.x;
    const int brow = by * 256;
    const int bcol = bx * 256;

    const int nT = K >> 6;            // K-tiles of 64

    // hoisted per-thread staging source pointers (row = tid>>3, slot = tid&7;
    // rows r0/r1 differ by 64 (= 0 mod 8) so the swizzle is identical)
    const int srow = tid >> 3;
    const int swz  = (((tid & 7) ^ (srow & 7)) << 3);
    const u16* pgA0 = A  + (size_t)(brow +       srow) * lda + swz;
    const u16* pgA1 = A  + (size_t)(brow + 128 + srow) * lda + swz;
    const u16* pgB0 = Bt + (size_t)(bcol +       srow) * ldb + swz;
    const u16* pgB1 = Bt + (size_t)(bcol + 128 + srow) * ldb + swz;

    // stage one half-tile: 2 x global_load_lds (linear LDS dest, swz'd source)
    auto stg = [&](const u16* base, int ldg, int tile, u16* l0) {
        __builtin_amdgcn_global_load_lds(AS1(base + tile * 64),
                                         AS3(l0 + tid * 8), 16, 0, 0);
        __builtin_amdgcn_global_load_lds(AS1(base + (size_t)64 * ldg + tile * 64),
                                         AS3(l0 + 4096 + tid * 8), 16, 0, 0);
    };

    // swizzled ds_read offsets (u16 units), all compile-time-indexed
    int a_off[8][2], b_off[4][2];
    #pragma unroll
    for (int m = 0; m < 8; ++m) {
        const int row = m * 16 + lr;
        #pragma unroll
        for (int ks = 0; ks < 2; ++ks)
            a_off[m][ks] = row * 64 + ((ks * 32 + kq * 8) ^ ((row & 7) << 3));
    }
    #pragma unroll
    for (int n = 0; n < 4; ++n) {
        const int row = (wc & 1) * 64 + n * 16 + lr;
        #pragma unroll
        for (int ks = 0; ks < 2; ++ks)
            b_off[n][ks] = row * 64 + ((ks * 32 + kq * 8) ^ ((row & 7) << 3));
    }

    f32x4 acc[8][4] = {};
    bf16x8 af[4][2], bf0[2][2], bf1[2][2];

#define RD_A(mh) { _Pragma("unroll") for (int m = 0; m < 4; ++m) \
                   _Pragma("unroll") for (int ks = 0; ks < 2; ++ks) \
                       af[m][ks] = *(const bf16x8*)&la[a_off[(mh)*4 + m][ks]]; }
#define RD_B0()  { _Pragma("unroll") for (int j = 0; j < 2; ++j) \
                   _Pragma("unroll") for (int ks = 0; ks < 2; ++ks) \
                       bf0[j][ks] = *(const bf16x8*)&lb_[b_off[j][ks]]; }
#define RD_B1()  { _Pragma("unroll") for (int j = 0; j < 2; ++j) \
                   _Pragma("unroll") for (int ks = 0; ks < 2; ++ks) \
                       bf1[j][ks] = *(const bf16x8*)&lb_[b_off[2 + j][ks]]; }
#define MMA(mh, nh, BF) { __builtin_amdgcn_s_setprio(1); \
                      _Pragma("unroll") for (int m = 0; m < 4; ++m) \
                      _Pragma("unroll") for (int j = 0; j < 2; ++j) \
                      _Pragma("unroll") for (int ks = 0; ks < 2; ++ks) \
                          acc[(mh)*4 + m][(nh)*2 + j] = \
                              __builtin_amdgcn_mfma_f32_16x16x32_bf16( \
                                  af[m][ks], BF[j][ks], acc[(mh)*4 + m][(nh)*2 + j], 0, 0, 0); \
                      __builtin_amdgcn_s_setprio(0); }
#define BARRIER()  asm volatile("s_barrier" ::: "memory")
#define SCHED0()   __builtin_amdgcn_sched_barrier(0)

    // prologue: tile0 fully + tile1's A (steady state stages A one iter early)
    stg(pgA0, lda, 0, &lds[0]);
    stg(pgA1, lda, 0, &lds[8192]);
    stg(pgB0, ldb, 0, &lds[32768]);
    stg(pgB1, ldb, 0, &lds[32768 + 8192]);
    if (nT > 1) {
        stg(pgA0, lda, 1, &lds[16384]);
        stg(pgA1, lda, 1, &lds[16384 + 8192]);
        asm volatile("s_waitcnt vmcnt(4)" ::: "memory");
    } else {
        asm volatile("s_waitcnt vmcnt(0)" ::: "memory");
    }
    BARRIER();

    for (int t = 0; t < nT; ++t) {
        const int b = t & 1;
        const u16* la  = &lds[b * 16384 + wr * 8192];
        const u16* lb_ = &lds[32768 + b * 16384 + (wc >> 1) * 8192];
        u16* stA = &lds[b * 16384];                 // tile t+2 parity == b
        u16* stB = &lds[32768 + (b ^ 1) * 16384];   // tile t+1 parity == b^1

        // ---- phase 0: quadrant (0,0) ----
        RD_A(0); RD_B0();
        if (t + 1 < nT) stg(pgB0, ldb, t + 1, stB);
        BARRIER(); SCHED0();
        MMA(0, 0, bf0);
        RD_B1();                       // overlap with matrix pipe
        BARRIER();

        // ---- phase 1: quadrant (0,1) ----
        if (t + 1 < nT) stg(pgB1, ldb, t + 1, stB + 8192);
        BARRIER(); SCHED0();
        MMA(0, 1, bf1);
        RD_A(1);                       // overlap with matrix pipe
        BARRIER();

        // ---- phase 2: quadrant (1,1) ----
        SCHED0();
        MMA(1, 1, bf1);
        BARRIER();

        // ---- phase 3: quadrant (1,0) — B0 kept in regs ----
        if (t + 2 < nT) { stg(pgA0, lda, t + 2, stA); stg(pgA1, lda, t + 2, stA + 8192); }
        BARRIER(); SCHED0();
        MMA(1, 0, bf0);
        if (t < nT - 2)       { asm volatile("s_waitcnt vmcnt(4)" ::: "memory"); }
        else if (t == nT - 2) { asm volatile("s_waitcnt vmcnt(0)" ::: "memory"); }
        BARRIER();
    }

#undef RD_A
#undef RD_B0
#undef RD_B1
#undef MMA
#undef BARRIER
#undef SCHED0

    // epilogue: sin(v + bias) -> bf16.  C/D map: col = lane&15, row = kq*4 + r
    float bv[4];
    #pragma unroll
    for (int n = 0; n < 4; ++n) bv[n] = bias[bcol + wc * 64 + n * 16 + lr];
    #pragma unroll
    for (int m = 0; m < 8; ++m) {
        const int row = brow + wr * 128 + m * 16 + kq * 4;
        #pragma unroll
        for (int n = 0; n < 4; ++n) {
            const int col = bcol + wc * 64 + n * 16 + lr;
            #pragma unroll
            for (int r = 0; r < 4; ++r)
                C[(size_t)(row + r) * ldc + col] = f2bf(__sinf(acc[m][n][r] + bv[n]));
        }
    }
}

// ---------------- launch ----------------

extern "C" void kernel_launch(void* const* d_in, const int* in_sizes, int n_in,
                              void* d_out, int out_size, void* d_ws, size_t ws_size,
                              hipStream_t stream) {
    const float* t  = (const float*)d_in[0];
    const float* W1 = (const float*)d_in[1];
    const float* b1 = (const float*)d_in[2];
    const float* W2 = (const float*)d_in[3];
    const float* b2 = (const float*)d_in[4];
    const float* W3 = (const float*)d_in[5];
    const float* b3 = (const float*)d_in[6];
    float* out = (float*)d_out;

    constexpr int B = 32768, Din = 64, H = 2048, Dout = 64;

    char* p = (char*)d_ws;
    u16* t_bf = (u16*)p; p += (size_t)B * Din * 2;
    u16* w1t  = (u16*)p; p += (size_t)H * Din * 2;
    u16* w2t  = (u16*)p; p += (size_t)H * H * 2;
    u16* w3t  = (u16*)p; p += (size_t)Dout * H * 2;
    size_t fixed = (size_t)(p - (char*)d_ws);

    int R = B;
    while (R > 512 && fixed + (size_t)2 * R * H * 2 > ws_size) R >>= 1;
    u16* h1 = (u16*)p;
    u16* h2 = (u16*)(p + (size_t)R * H * 2);

    k_f32_to_bf16<<<(B * Din + 255) / 256, 256, 0, stream>>>(t, t_bf, B * Din);
    k_transpose_bf16<<<dim3(H / 32, Din / 32), dim3(32, 8), 0, stream>>>(W1, w1t, Din, H);
    k_transpose_bf16<<<dim3(H / 32, H / 32), dim3(32, 8), 0, stream>>>(W2, w2t, H, H);
    k_transpose_bf16<<<dim3(Dout / 32, H / 32), dim3(32, 8), 0, stream>>>(W3, w3t, H, Dout);
    k_init_out<<<(out_size + 255) / 256, 256, 0, stream>>>(b3, out, out_size);

    const int SPLITS = 4;
    for (int c0 = 0; c0 < B; c0 += R) {
        const u16* tA = t_bf + (size_t)c0 * Din;
        // GEMM1: h1 = J1(t@W1 + b1)   [R x H], K=64
        k_gemm_bt<128, 128, 4, 4, 0><<<dim3(H / 128, R / 128), 256, 0, stream>>>(
            tA, Din, w1t, Din, b1, h1, H, 0, Din);
        // GEMM2: h2 = sin(h1@W2 + b2) [R x H], K=2048 — 256^2 8-phase kernel
        k_gemm256<<<dim3(H / 256, R / 256), 512, 0, stream>>>(
            h1, H, w2t, H, b2, h2, H, H);
        // GEMM3: out += h2@W3 (b3 pre-initialized), split-K=4, atomic f32
        k_gemm_bt<128, 64, 4, 2, 2><<<dim3(1, R / 128, SPLITS), 256, 0, stream>>>(
            h2, H, w3t, H, nullptr, out + (size_t)c0 * Dout, Dout, 0, H / SPLITS);
    }
}

// Round 7
// 379.133 us; speedup vs baseline: 1.2882x; 1.0238x over previous
//
#include <hip/hip_runtime.h>
#include <cstdint>
#include <cstddef>

typedef unsigned short u16;
typedef __attribute__((ext_vector_type(8))) __bf16 bf16x8;
typedef __attribute__((ext_vector_type(4))) float f32x4;

#define AS1(p) ((const __attribute__((address_space(1))) void*)(p))
#define AS3(p) ((__attribute__((address_space(3))) void*)(p))

// ---------------- helpers ----------------

__device__ __forceinline__ u16 f2bf(float f) {
    union { float f; unsigned u; } v; v.f = f;
    unsigned r = v.u + 0x7fffu + ((v.u >> 16) & 1u);   // round-to-nearest-even
    return (u16)(r >> 16);
}

__device__ __forceinline__ float j1f_approx(float x) {
    float ax = fabsf(x);
    float y = x * x;
    float num = x * (7.2362614232e10f + y * (-7.895059235e9f + y * (2.423968531e8f
              + y * (-2.972611439e6f + y * (1.570448260e4f + y * (-3.016036606e1f))))));
    float den = 1.44725228442e11f + y * (2.300535178e9f + y * (1.858330474e7f
              + y * (9.944743394e4f + y * (3.769991397e2f + y))));
    float r = num / den;
    if (__any(ax >= 8.0f)) {
        float z  = 8.0f / ax;
        float yy = z * z;
        float xx = ax - 2.356194491f;
        float p1 = 1.0f + yy * (0.183105e-2f + yy * (-0.3516396496e-4f
                 + yy * (0.2457520174e-5f + yy * (-0.240337019e-6f))));
        float p2 = 0.04687499995f + yy * (-0.2002690873e-3f + yy * (0.8449199096e-5f
                 + yy * (-0.88228987e-6f + yy * 0.105787412e-6f)));
        float big = sqrtf(0.636619772f / ax) * (__cosf(xx) * p1 - z * __sinf(xx) * p2);
        big = copysignf(big, x);
        if (ax >= 8.0f) r = big;
    }
    return r;
}

// ---------------- prep kernels ----------------

__global__ void k_f32_to_bf16(const float* __restrict__ in, u16* __restrict__ out, int n) {
    int i = blockIdx.x * 256 + threadIdx.x;
    if (i < n) out[i] = f2bf(in[i]);
}

__global__ void k_transpose_bf16(const float* __restrict__ in, u16* __restrict__ out,
                                 int K, int N) {
    __shared__ float tile[32][33];
    int n0 = blockIdx.x * 32, k0 = blockIdx.y * 32;
    int tx = threadIdx.x, ty = threadIdx.y;   // 32 x 8
    #pragma unroll
    for (int i = ty; i < 32; i += 8)
        tile[i][tx] = in[(size_t)(k0 + i) * N + n0 + tx];
    __syncthreads();
    #pragma unroll
    for (int i = ty; i < 32; i += 8)
        out[(size_t)(n0 + i) * K + k0 + tx] = f2bf(tile[tx][i]);
}

__global__ void k_init_out(const float* __restrict__ b3, float* __restrict__ out, int n) {
    int i = blockIdx.x * 256 + threadIdx.x;
    if (i < n) out[i] = b3[i & 63];
}

// ---------------- small GEMM (m97 128^2 structure) for GEMM1 / GEMM3 ----------------
// C[M,N] = A[M,K] * Bt[N,K]^T.  EPI: 0 = J1(v+bias)->bf16, 2 = atomicAdd f32.

#define BK 32

template<int BM, int BN, int WTM, int WTN, int EPI>
__global__ __launch_bounds__(256)
void k_gemm_bt(const u16* __restrict__ A, int lda,
               const u16* __restrict__ Bt, int ldb,
               const float* __restrict__ bias,
               void* __restrict__ Cout, int ldc,
               int kstart, int klen)
{
    __shared__ __align__(16) u16 Alds[BM * BK];
    __shared__ __align__(16) u16 Blds[BN * BK];

    const int tid  = threadIdx.x;
    const int lane = tid & 63;
    const int wid  = tid >> 6;
    const int wrow = (wid >> 1) * (WTM * 16);
    const int wcol = (wid & 1) * (WTN * 16);
    const int lr   = lane & 15;
    const int lkb  = (lane >> 4) * 8;

    const int brow = blockIdx.y * BM;
    const int bcol = blockIdx.x * BN;
    const int k0 = kstart + blockIdx.z * klen;
    const int k1 = k0 + klen;

    f32x4 acc[WTM][WTN] = {};

    for (int kk = k0; kk < k1; kk += BK) {
        #pragma unroll
        for (int c = tid; c < BM * 4; c += 256) {
            const u16* g = A + (size_t)(brow + (c >> 2)) * lda + kk + (c & 3) * 8;
            __builtin_amdgcn_global_load_lds(AS1(g), AS3(&Alds[c * 8]), 16, 0, 0);
        }
        #pragma unroll
        for (int c = tid; c < BN * 4; c += 256) {
            const u16* g = Bt + (size_t)(bcol + (c >> 2)) * ldb + kk + (c & 3) * 8;
            __builtin_amdgcn_global_load_lds(AS1(g), AS3(&Blds[c * 8]), 16, 0, 0);
        }
        __syncthreads();

        bf16x8 af[WTM], bfr[WTN];
        #pragma unroll
        for (int m = 0; m < WTM; ++m)
            af[m] = *(const bf16x8*)&Alds[(wrow + m * 16 + lr) * BK + lkb];
        #pragma unroll
        for (int n = 0; n < WTN; ++n)
            bfr[n] = *(const bf16x8*)&Blds[(wcol + n * 16 + lr) * BK + lkb];
        #pragma unroll
        for (int m = 0; m < WTM; ++m)
            #pragma unroll
            for (int n = 0; n < WTN; ++n)
                acc[m][n] = __builtin_amdgcn_mfma_f32_16x16x32_bf16(
                                af[m], bfr[n], acc[m][n], 0, 0, 0);
        __syncthreads();
    }

    const int rbase = brow + wrow + (lane >> 4) * 4;
    const int cbase = bcol + wcol + lr;
    #pragma unroll
    for (int n = 0; n < WTN; ++n) {
        const int col = cbase + n * 16;
        float bv = 0.0f;
        if constexpr (EPI != 2) bv = bias[col];
        #pragma unroll
        for (int m = 0; m < WTM; ++m) {
            #pragma unroll
            for (int r = 0; r < 4; ++r) {
                const int row = rbase + m * 16 + r;
                float v = acc[m][n][r];
                if constexpr (EPI == 0) {
                    ((u16*)Cout)[(size_t)row * ldc + col] = f2bf(j1f_approx(v + bv));
                } else {
                    atomicAdd(&((float*)Cout)[(size_t)row * ldc + col], v);
                }
            }
        }
    }
}

// ---------------- 256^2 GEMM for GEMM2 — minimal-barrier pipelined schedule ----
// C[M,N] = A[M,K]*Bt[N,K]^T, epilogue sin(v+bias)->bf16.
// 512 threads = 8 waves (2 M-halves x 4 N-quarters). BK=64, dbuf LDS 128 KiB.
// SEPARATE fragment buffers af0/af1 (round-5/6 bug: single af buffer made
// MMA(0,1) consume A-half-1 after RD_A(1) overwrote it — WAR hazard).
// 2 barriers per K-tile:
//  (i)  lgkmcnt(0) + barrier after ALL of tile t's ds_reads are SERVICED
//       (af1's reads are unconsumed at this point, so the drain is required
//       before other waves may overwrite A-buf b) -> A(t+2) staging safe.
//  (ii) end-of-tile: per-wave vmcnt(4) then barrier — barrier release proves
//       ALL waves' B(t+1) stages landed; A(t+2)'s 4 loads stay in flight
//       (consumed 2 tiles later, covered by the next tile's vmcnt(4)).
// Staging (iter t, buf b = t&1): B-h0/h1(t+1) -> B-buf b^1 (its reads drained
// before barrier (i) of t-1); A-h0/h1(t+2) -> A-buf b after barrier (i).

__global__ __launch_bounds__(512, 2)
void k_gemm256(const u16* __restrict__ A, int lda,
               const u16* __restrict__ Bt, int ldb,
               const float* __restrict__ bias,
               u16* __restrict__ C, int ldc, int K)
{
    __shared__ __align__(16) u16 lds[65536];   // 128 KiB

    const int tid  = threadIdx.x;
    const int lane = tid & 63;
    const int wid  = tid >> 6;
    const int wr   = wid >> 2;        // 0..1  (M half, 128 rows)
    const int wc   = wid & 3;         // 0..3  (N quarter, 64 cols)
    const int lr   = lane & 15;
    const int kq   = lane >> 4;       // 0..3

    // XCD-bijective block swizzle (gridDim.x == 8 -> nwg % 8 == 0)
    const int nwg  = gridDim.x * gridDim.y;
    const int bid0 = blockIdx.y * gridDim.x + blockIdx.x;
    const int wg   = (bid0 & 7) * (nwg >> 3) + (bid0 >> 3);
    const int bx   = wg % gridDim.x;
    const int by   = wg / gridDim.x;
    const int brow = by * 256;
    const int bcol = bx * 256;

    const int nT = K >> 6;            // K-tiles of 64

    // hoisted per-thread staging source pointers (row = tid>>3, slot = tid&7;
    // rows r and r+64 have identical swizzle since 64 % 8 == 0)
    const int srow = tid >> 3;
    const int swz  = (((tid & 7) ^ (srow & 7)) << 3);
    const u16* pgA0 = A  + (size_t)(brow +       srow) * lda + swz;
    const u16* pgA1 = A  + (size_t)(brow + 128 + srow) * lda + swz;
    const u16* pgB0 = Bt + (size_t)(bcol +       srow) * ldb + swz;
    const u16* pgB1 = Bt + (size_t)(bcol + 128 + srow) * ldb + swz;

    // stage one half-tile: 2 x global_load_lds (linear LDS dest, swz'd source)
    auto stg = [&](const u16* base, int ldg, int tile, u16* l0) {
        __builtin_amdgcn_global_load_lds(AS1(base + tile * 64),
                                         AS3(l0 + tid * 8), 16, 0, 0);
        __builtin_amdgcn_global_load_lds(AS1(base + (size_t)64 * ldg + tile * 64),
                                         AS3(l0 + 4096 + tid * 8), 16, 0, 0);
    };

    // swizzled ds_read offsets (u16 units), all compile-time-indexed
    int a_off[8][2], b_off[4][2];
    #pragma unroll
    for (int m = 0; m < 8; ++m) {
        const int row = m * 16 + lr;
        #pragma unroll
        for (int ks = 0; ks < 2; ++ks)
            a_off[m][ks] = row * 64 + ((ks * 32 + kq * 8) ^ ((row & 7) << 3));
    }
    #pragma unroll
    for (int n = 0; n < 4; ++n) {
        const int row = (wc & 1) * 64 + n * 16 + lr;
        #pragma unroll
        for (int ks = 0; ks < 2; ++ks)
            b_off[n][ks] = row * 64 + ((ks * 32 + kq * 8) ^ ((row & 7) << 3));
    }

    f32x4 acc[8][4] = {};
    bf16x8 af0[4][2], af1[4][2], bf0[2][2], bf1[2][2];

#define RD_A(mh, AF) { _Pragma("unroll") for (int m = 0; m < 4; ++m) \
                   _Pragma("unroll") for (int ks = 0; ks < 2; ++ks) \
                       AF[m][ks] = *(const bf16x8*)&la[a_off[(mh)*4 + m][ks]]; }
#define RD_B0()  { _Pragma("unroll") for (int j = 0; j < 2; ++j) \
                   _Pragma("unroll") for (int ks = 0; ks < 2; ++ks) \
                       bf0[j][ks] = *(const bf16x8*)&lb_[b_off[j][ks]]; }
#define RD_B1()  { _Pragma("unroll") for (int j = 0; j < 2; ++j) \
                   _Pragma("unroll") for (int ks = 0; ks < 2; ++ks) \
                       bf1[j][ks] = *(const bf16x8*)&lb_[b_off[2 + j][ks]]; }
#define MMA(mh, nh, AF, BF) { __builtin_amdgcn_s_setprio(1); \
                      _Pragma("unroll") for (int m = 0; m < 4; ++m) \
                      _Pragma("unroll") for (int j = 0; j < 2; ++j) \
                      _Pragma("unroll") for (int ks = 0; ks < 2; ++ks) \
                          acc[(mh)*4 + m][(nh)*2 + j] = \
                              __builtin_amdgcn_mfma_f32_16x16x32_bf16( \
                                  AF[m][ks], BF[j][ks], acc[(mh)*4 + m][(nh)*2 + j], 0, 0, 0); \
                      __builtin_amdgcn_s_setprio(0); }
#define BARRIER()  asm volatile("s_barrier" ::: "memory")
#define LGKM0()    asm volatile("s_waitcnt lgkmcnt(0)" ::: "memory")

    // prologue: tile0 fully + tile1's A (steady state stages A one iter early)
    stg(pgA0, lda, 0, &lds[0]);
    stg(pgA1, lda, 0, &lds[8192]);
    stg(pgB0, ldb, 0, &lds[32768]);
    stg(pgB1, ldb, 0, &lds[32768 + 8192]);
    if (nT > 1) {
        stg(pgA0, lda, 1, &lds[16384]);
        stg(pgA1, lda, 1, &lds[16384 + 8192]);
        asm volatile("s_waitcnt vmcnt(4)" ::: "memory");
    } else {
        asm volatile("s_waitcnt vmcnt(0)" ::: "memory");
    }
    BARRIER();

    for (int t = 0; t < nT; ++t) {
        const int b = t & 1;
        const u16* la  = &lds[b * 16384 + wr * 8192];
        const u16* lb_ = &lds[32768 + b * 16384 + (wc >> 1) * 8192];
        u16* stA = &lds[b * 16384];                 // tile t+2 parity == b
        u16* stB = &lds[32768 + (b ^ 1) * 16384];   // tile t+1 parity == b^1

        // first half: all ds_reads of tile t issue here; B(t+1) staging
        RD_A(0, af0); RD_B0();
        if (t + 1 < nT) stg(pgB0, ldb, t + 1, stB);
        MMA(0, 0, af0, bf0);
        RD_B1(); RD_A(1, af1);
        if (t + 1 < nT) stg(pgB1, ldb, t + 1, stB + 8192);
        MMA(0, 1, af0, bf1);

        LGKM0();     // drain: all of tile t's ds_reads SERVICED before overwrite
        BARRIER();   // (i): A-buf b overwrite now safe for every wave

        if (t + 2 < nT) { stg(pgA0, lda, t + 2, stA); stg(pgA1, lda, t + 2, stA + 8192); }
        MMA(1, 1, af1, bf1);
        MMA(1, 0, af1, bf0);

        if (t < nT - 2)       { asm volatile("s_waitcnt vmcnt(4)" ::: "memory"); }
        else if (t == nT - 2) { asm volatile("s_waitcnt vmcnt(0)" ::: "memory"); }
        BARRIER();   // (ii): vmcnt precedes arrival -> all waves' B(t+1) landed
    }

#undef RD_A
#undef RD_B0
#undef RD_B1
#undef MMA
#undef BARRIER
#undef LGKM0

    // epilogue: sin(v + bias) -> bf16.  C/D map: col = lane&15, row = kq*4 + r
    float bv[4];
    #pragma unroll
    for (int n = 0; n < 4; ++n) bv[n] = bias[bcol + wc * 64 + n * 16 + lr];
    #pragma unroll
    for (int m = 0; m < 8; ++m) {
        const int row = brow + wr * 128 + m * 16 + kq * 4;
        #pragma unroll
        for (int n = 0; n < 4; ++n) {
            const int col = bcol + wc * 64 + n * 16 + lr;
            #pragma unroll
            for (int r = 0; r < 4; ++r)
                C[(size_t)(row + r) * ldc + col] = f2bf(__sinf(acc[m][n][r] + bv[n]));
        }
    }
}

// ---------------- launch ----------------

extern "C" void kernel_launch(void* const* d_in, const int* in_sizes, int n_in,
                              void* d_out, int out_size, void* d_ws, size_t ws_size,
                              hipStream_t stream) {
    const float* t  = (const float*)d_in[0];
    const float* W1 = (const float*)d_in[1];
    const float* b1 = (const float*)d_in[2];
    const float* W2 = (const float*)d_in[3];
    const float* b2 = (const float*)d_in[4];
    const float* W3 = (const float*)d_in[5];
    const float* b3 = (const float*)d_in[6];
    float* out = (float*)d_out;

    constexpr int B = 32768, Din = 64, H = 2048, Dout = 64;

    char* p = (char*)d_ws;
    u16* t_bf = (u16*)p; p += (size_t)B * Din * 2;
    u16* w1t  = (u16*)p; p += (size_t)H * Din * 2;
    u16* w2t  = (u16*)p; p += (size_t)H * H * 2;
    u16* w3t  = (u16*)p; p += (size_t)Dout * H * 2;
    size_t fixed = (size_t)(p - (char*)d_ws);

    int R = B;
    while (R > 512 && fixed + (size_t)2 * R * H * 2 > ws_size) R >>= 1;
    u16* h1 = (u16*)p;
    u16* h2 = (u16*)(p + (size_t)R * H * 2);

    k_f32_to_bf16<<<(B * Din + 255) / 256, 256, 0, stream>>>(t, t_bf, B * Din);
    k_transpose_bf16<<<dim3(H / 32, Din / 32), dim3(32, 8), 0, stream>>>(W1, w1t, Din, H);
    k_transpose_bf16<<<dim3(H / 32, H / 32), dim3(32, 8), 0, stream>>>(W2, w2t, H, H);
    k_transpose_bf16<<<dim3(Dout / 32, H / 32), dim3(32, 8), 0, stream>>>(W3, w3t, H, Dout);
    k_init_out<<<(out_size + 255) / 256, 256, 0, stream>>>(b3, out, out_size);

    const int SPLITS = 4;
    for (int c0 = 0; c0 < B; c0 += R) {
        const u16* tA = t_bf + (size_t)c0 * Din;
        // GEMM1: h1 = J1(t@W1 + b1)   [R x H], K=64
        k_gemm_bt<128, 128, 4, 4, 0><<<dim3(H / 128, R / 128), 256, 0, stream>>>(
            tA, Din, w1t, Din, b1, h1, H, 0, Din);
        // GEMM2: h2 = sin(h1@W2 + b2) [R x H], K=2048 — 256^2 minimal-barrier
        k_gemm256<<<dim3(H / 256, R / 256), 512, 0, stream>>>(
            h1, H, w2t, H, b2, h2, H, H);
        // GEMM3: out += h2@W3 (b3 pre-initialized), split-K=4, atomic f32
        k_gemm_bt<128, 64, 4, 2, 2><<<dim3(1, R / 128, SPLITS), 256, 0, stream>>>(
            h2, H, w3t, H, nullptr, out + (size_t)c0 * Dout, Dout, 0, H / SPLITS);
    }
}